// Round 2
// baseline (246.573 us; speedup 1.0000x reference)
//
#include <hip/hip_runtime.h>

// x: [2,64,32,32,32] f32 | weight: [128,64,3,3,3] f32 | bias:[128]
// lora_A: [16,1728] | lora_B: [128,16] | out: [2,128,32,32,32] f32 | SCALING = 2.0
//
// Pipeline:
//  memset xt, lowp (halo zeros)
//  transpose: x -> xt[b][34][34][34][64] bf16 (padded, zero halo)
//  wct: weights+lora_A -> Wc_t[144][1728] bf16, k = off*64 + c
//  gemm: barrier-free, LDS-free implicit GEMM; M=144 (128 conv + 16 rank),
//        B-frags loaded per-lane direct from padded xt; epilogue -> out (+bias)
//        and padded lowp[2][16][34^3]
//  foldlow: fl[b][r][p] = 27-neighbor sum of lowp (halo makes it branch-free)
//  mix: out[b][o][p] += 2 * sum_r lora_B[o][r] * fl[b][r][p]

typedef __attribute__((ext_vector_type(8))) short short8;
typedef __attribute__((ext_vector_type(4))) float float4v;

#define PV 39304   // 34*34*34
#define PH 1156    // 34*34

__device__ inline unsigned short f2bf(float f) {
    unsigned int u = __float_as_uint(f);
    unsigned int r = u + 0x7FFFu + ((u >> 16) & 1u);
    return (unsigned short)(r >> 16);
}

// x [b,c,p] f32  ->  xt [b][d+1][h+1][w+1][c] bf16 (padded 34^3, halo pre-zeroed)
__global__ __launch_bounds__(256) void transpose_kernel(const float* __restrict__ x,
                                                        unsigned short* __restrict__ xt) {
    __shared__ float tile[64][65];
    int t = threadIdx.x;
    int blk = blockIdx.x;            // 1024 blocks: 2 b * 512 tiles (64 pos each)
    int b = blk >> 9;
    int p0 = (blk & 511) * 64;
    int d = p0 >> 10;
    int h0 = (p0 >> 5) & 31;         // tile covers rows h0, h0+1, all w
#pragma unroll
    for (int it = 0; it < 16; ++it) {
        int idx = it * 256 + t;
        int c = idx >> 6, pp = idx & 63;
        tile[c][pp] = x[((size_t)(b * 64 + c) << 15) + p0 + pp];
    }
    __syncthreads();
#pragma unroll
    for (int it = 0; it < 8; ++it) {
        int idx = it * 256 + t;
        int pp = idx >> 5, cp = idx & 31;
        unsigned int u0 = f2bf(tile[cp * 2][pp]);
        unsigned int u1 = f2bf(tile[cp * 2 + 1][pp]);
        int h = h0 + (pp >> 5);
        int w = pp & 31;
        size_t pidx = (size_t)((b * 34 + d + 1) * 34 + h + 1) * 34 + w + 1;
        *(unsigned int*)(xt + pidx * 64 + cp * 2) = u0 | (u1 << 16);
    }
}

// Wc_t[144][1728] bf16, k = off*64 + c
__global__ void wct_kernel(const float* __restrict__ weight,
                           const float* __restrict__ loraA,
                           unsigned short* __restrict__ wct) {
    int n = blockIdx.y;
    int k = blockIdx.x * 64 + threadIdx.x;   // grid.x = 27, block = 64
    int off = k >> 6;
    int c = k & 63;
    float v;
    if (n < 128) v = weight[(n * 64 + c) * 27 + off];
    else         v = loraA[(n - 128) * 1728 + c * 27 + off];
    wct[n * 1728 + k] = f2bf(v);
}

// Barrier-free implicit GEMM. Block = 4 waves; wave = 1 h-row x 32 w (32 pos,
// 2 B-frags); M = 144 in 9 A-frags. 512 blocks (2/CU -> 2 waves/SIMD).
__global__ __launch_bounds__(256, 2) void gemm_kernel(const unsigned short* __restrict__ xt,
                                                      const unsigned short* __restrict__ wct,
                                                      const float* __restrict__ bias,
                                                      float* __restrict__ out,
                                                      float* __restrict__ lowp) {
    int t = threadIdx.x;
    int wv = t >> 6;
    int lane = t & 63;
    int l16 = lane & 15;
    int quad = lane >> 4;

    int tt = blockIdx.x;             // 512
    int b = tt >> 8;
    int d = (tt >> 3) & 31;
    int h0 = (tt & 7) * 4;
    int h = h0 + wv;

    // per-lane base into padded xt; kb adds scalar offset; f adds 16*64
    int pbase = (((b * 34 + d) * 34 + h) * 34 + l16) * 64 + quad * 8;
    // per-lane base into wct; nf adds 16*1728
    int wbase = l16 * 1728 + quad * 8;

    float4v acc[9][2];
#pragma unroll
    for (int nf = 0; nf < 9; ++nf)
#pragma unroll
        for (int f = 0; f < 2; ++f) acc[nf][f] = (float4v){0.f, 0.f, 0.f, 0.f};

    for (int kb = 0; kb < 27; ++kb) {
        int ki = kb / 9;
        int kj = (kb / 3) % 3;
        int kl = kb % 3;
        int koff = ((ki * 34 + kj) * 34 + kl) * 64;   // scalar (wave-uniform)
        int wkoff = kb * 64;

#pragma unroll
        for (int ks = 0; ks < 2; ++ks) {
            // issue all loads of this ks-step before the MFMAs
            short8 bf0 = *(const short8*)(xt + pbase + koff + ks * 32);
            short8 bf1 = *(const short8*)(xt + pbase + 1024 + koff + ks * 32);
            short8 af[9];
#pragma unroll
            for (int nf = 0; nf < 9; ++nf)
                af[nf] = *(const short8*)(wct + wbase + nf * 27648 + wkoff + ks * 32);
#pragma unroll
            for (int nf = 0; nf < 9; ++nf) {
                acc[nf][0] = __builtin_amdgcn_mfma_f32_16x16x32_bf16(af[nf], bf0, acc[nf][0], 0, 0, 0);
                acc[nf][1] = __builtin_amdgcn_mfma_f32_16x16x32_bf16(af[nf], bf1, acc[nf][1], 0, 0, 0);
            }
        }
    }

#pragma unroll
    for (int f = 0; f < 2; ++f) {
        int w = f * 16 + l16;
        int p = d * 1024 + h * 32 + w;
#pragma unroll
        for (int nf = 0; nf < 9; ++nf) {
#pragma unroll
            for (int r = 0; r < 4; ++r) {
                int o = nf * 16 + quad * 4 + r;
                float v = acc[nf][f][r];
                if (o < 128) {
                    out[((size_t)(b * 128 + o) << 15) + p] = v + bias[o];
                } else {
                    size_t li = (size_t)(b * 16 + (o - 128)) * PV +
                                (size_t)(d + 1) * PH + (h + 1) * 34 + (w + 1);
                    lowp[li] = v;
                }
            }
        }
    }
}

// fl[b][r][p] = 27-neighbor sum of lowp (branch-free via halo)
__global__ __launch_bounds__(256) void foldlow_kernel(const float* __restrict__ lowp,
                                                      float* __restrict__ fl) {
    int gid = blockIdx.x * 256 + threadIdx.x;   // 4096 blocks, 1,048,576 threads
    int p = gid & 32767;
    int r = (gid >> 15) & 15;
    int b = gid >> 19;
    int d = p >> 10, h = (p >> 5) & 31, w = p & 31;
    const float* base = lowp + (size_t)(b * 16 + r) * PV +
                        (size_t)(d + 1) * PH + (h + 1) * 34 + (w + 1);
    float s = 0.f;
#pragma unroll
    for (int dd = -1; dd <= 1; ++dd)
#pragma unroll
        for (int dh = -1; dh <= 1; ++dh)
#pragma unroll
            for (int dw = -1; dw <= 1; ++dw)
                s += base[dd * PH + dh * 34 + dw];
    fl[gid] = s;
}

// out[b][o][p] += 2 * sum_r lora_B[o][r] * fl[b][r][p]
__global__ __launch_bounds__(256) void mix_kernel(const float* __restrict__ fl,
                                                  const float* __restrict__ loraB,
                                                  float* __restrict__ out) {
    __shared__ float lB[2048];
    int t = threadIdx.x;
    for (int i = t; i < 2048; i += 256) lB[i] = loraB[i];
    __syncthreads();

    int wv = t >> 6;
    int lane = t & 63;
    int P = blockIdx.x * 64 + lane;   // 1024 blocks cover 65536 global positions
    int b = P >> 15;
    int p = P & 32767;

    float f[16];
#pragma unroll
    for (int r = 0; r < 16; ++r) f[r] = fl[((size_t)(b * 16 + r) << 15) + p];

    float* op = out + ((size_t)(b * 128) << 15) + p;
    int o0 = wv * 32;
#pragma unroll
    for (int oi = 0; oi < 32; ++oi) {
        int o = o0 + oi;
        float s = 0.f;
#pragma unroll
        for (int r = 0; r < 16; ++r) s += lB[o * 16 + r] * f[r];
        op[(size_t)o << 15] += 2.0f * s;
    }
}

extern "C" void kernel_launch(void* const* d_in, const int* in_sizes, int n_in,
                              void* d_out, int out_size, void* d_ws, size_t ws_size,
                              hipStream_t stream) {
    const float* x      = (const float*)d_in[0];
    const float* weight = (const float*)d_in[1];
    const float* bias   = (const float*)d_in[2];
    const float* loraA  = (const float*)d_in[3];
    const float* loraB  = (const float*)d_in[4];
    float* out = (float*)d_out;

    char* ws = (char*)d_ws;
    unsigned short* xt  = (unsigned short*)ws;                      // 2*39304*64*2 = 10,061,824 B
    unsigned short* wct = (unsigned short*)(ws + 10061824);         // 144*1728*2   =    497,664 B
    float* lowp         = (float*)(ws + 10559488);                  // 2*16*39304*4 =  5,030,912 B
    float* fl           = (float*)(ws + 15590400);                  // 2*16*32768*4 =  4,194,304 B

    hipMemsetAsync(xt, 0, 10061824, stream);
    hipMemsetAsync(lowp, 0, 5030912, stream);
    hipLaunchKernelGGL(transpose_kernel, dim3(1024), dim3(256), 0, stream, x, xt);
    hipLaunchKernelGGL(wct_kernel, dim3(27, 144), dim3(64), 0, stream, weight, loraA, wct);
    hipLaunchKernelGGL(gemm_kernel, dim3(512), dim3(256), 0, stream, xt, wct, bias, out, lowp);
    hipLaunchKernelGGL(foldlow_kernel, dim3(4096), dim3(256), 0, stream, lowp, fl);
    hipLaunchKernelGGL(mix_kernel, dim3(1024), dim3(256), 0, stream, fl, loraB, out);
}

// Round 3
// 194.917 us; speedup vs baseline: 1.2650x; 1.2650x over previous
//
#include <hip/hip_runtime.h>

// x: [2,64,32,32,32] f32 | weight: [128,64,3,3,3] f32 | bias:[128]
// lora_A: [16,1728] | lora_B: [128,16] | out: [2,128,32,32,32] f32 | SCALING = 2.0
//
// prep:   x -> xt[b][34][34][34][64] bf16 (zero halo), weights+lora_A ->
//         wpack in MFMA-A-fragment order [(kb*2+ks)*9+nf][lane][8] (coalesced!)
// gemm:   barrier-free LDS-free implicit GEMM, M=144 (128 conv + 16 rank),
//         2-deep software pipeline; epilogue -> cbuf (bf16 conv+bias) + low
// foldlow: fl[b][r][p] = 27-neighbor overlap-add of low (bounds-checked)
// mix:    out = cbuf + 2 * lora_B . fl

typedef __attribute__((ext_vector_type(8))) short short8;
typedef __attribute__((ext_vector_type(4))) float float4v;

#define PV 39304   // 34^3
#define PH 1156    // 34^2

__device__ inline unsigned short f2bf(float f) {
    unsigned int u = __float_as_uint(f);
    unsigned int r = u + 0x7FFFu + ((u >> 16) & 1u);
    return (unsigned short)(r >> 16);
}

// grid = 1024 (transpose) + 308 (halo zero) + 122 (weight pack)
__global__ __launch_bounds__(256) void prep_kernel(const float* __restrict__ x,
                                                   const float* __restrict__ weight,
                                                   const float* __restrict__ loraA,
                                                   unsigned short* __restrict__ xt,
                                                   unsigned short* __restrict__ wpack) {
    int t = threadIdx.x;
    int blk = blockIdx.x;
    if (blk < 1024) {
        __shared__ float tile[64][65];
        int b = blk >> 9;
        int p0 = (blk & 511) * 64;
        int d = p0 >> 10;
        int h0 = (p0 >> 5) & 31;
#pragma unroll
        for (int it = 0; it < 16; ++it) {
            int idx = it * 256 + t;
            int c = idx >> 6, pp = idx & 63;
            tile[c][pp] = x[((size_t)(b * 64 + c) << 15) + p0 + pp];
        }
        __syncthreads();
#pragma unroll
        for (int it = 0; it < 8; ++it) {
            int idx = it * 256 + t;
            int pp = idx >> 5, cp = idx & 31;
            unsigned int u0 = f2bf(tile[cp * 2][pp]);
            unsigned int u1 = f2bf(tile[cp * 2 + 1][pp]);
            int h = h0 + (pp >> 5);
            int w = pp & 31;
            size_t pidx = (size_t)((b * 34 + d + 1) * 34 + h + 1) * 34 + w + 1;
            *(unsigned int*)(xt + pidx * 64 + cp * 2) = u0 | (u1 << 16);
        }
    } else if (blk < 1332) {
        int idx = (blk - 1024) * 256 + t;     // over 2*39304 padded positions
        if (idx < 78608) {
            int b = idx / PV;
            int pp = idx - b * PV;
            int d = pp / PH;
            int r2 = pp - d * PH;
            int h = r2 / 34;
            int w = r2 - h * 34;
            if (d == 0 || d == 33 || h == 0 || h == 33 || w == 0 || w == 33) {
                uint4 z = {0u, 0u, 0u, 0u};
                uint4* dst = (uint4*)(xt + (size_t)idx * 64);
#pragma unroll
                for (int i = 0; i < 8; ++i) dst[i] = z;
            }
        }
    } else {
        int gid = (blk - 1332) * 256 + t;     // 486 frags * 64 lanes = 31104
        if (gid < 31104) {
            int frag = gid >> 6, lane = gid & 63;
            int kb = frag / 18;
            int r18 = frag - kb * 18;
            int ks = r18 / 9;
            int nf = r18 - ks * 9;
            int l16 = lane & 15, quad = lane >> 4;
            int n = nf * 16 + l16;
            int c0 = ks * 32 + quad * 8;
            unsigned int u[4];
#pragma unroll
            for (int jp = 0; jp < 4; ++jp) {
                int ca = c0 + jp * 2, cb = ca + 1;
                float v0, v1;
                if (n < 128) {
                    v0 = weight[(n * 64 + ca) * 27 + kb];
                    v1 = weight[(n * 64 + cb) * 27 + kb];
                } else {
                    v0 = loraA[(n - 128) * 1728 + ca * 27 + kb];
                    v1 = loraA[(n - 128) * 1728 + cb * 27 + kb];
                }
                u[jp] = (unsigned)f2bf(v0) | ((unsigned)f2bf(v1) << 16);
            }
            uint4 val; val.x = u[0]; val.y = u[1]; val.z = u[2]; val.w = u[3];
            *(uint4*)(wpack + (size_t)gid * 8) = val;
        }
    }
}

// 512 blocks, 4 waves; wave = 1 h-row x 32 w; M = 144 in 9 A-frags.
__global__ __launch_bounds__(256) void gemm_kernel(const unsigned short* __restrict__ xt,
                                                   const unsigned short* __restrict__ wpack,
                                                   const float* __restrict__ bias,
                                                   float* __restrict__ out,
                                                   unsigned short* __restrict__ cbuf,
                                                   float* __restrict__ low,
                                                   int use_cbuf) {
    int t = threadIdx.x;
    int wv = t >> 6;
    int lane = t & 63;
    int l16 = lane & 15;
    int quad = lane >> 4;

    int tt = blockIdx.x;             // 512
    int b = tt >> 8;
    int d = (tt >> 3) & 31;
    int h = (tt & 7) * 4 + wv;

    int pbase = (((b * 34 + d) * 34 + h) * 34 + l16) * 64 + quad * 8;
    int wbase = lane * 8;

    float4v acc[9][2];
#pragma unroll
    for (int nf = 0; nf < 9; ++nf)
#pragma unroll
        for (int f = 0; f < 2; ++f) acc[nf][f] = (float4v){0.f, 0.f, 0.f, 0.f};

    short8 b0[2], b1[2], a[2][9];

    auto loadstep = [&](int s, int buf) {
        int kb = s >> 1, ks = s & 1;
        int ki = kb / 9;
        int kjl = kb - ki * 9;
        int kj = kjl / 3;
        int kl = kjl - kj * 3;
        int koff = ki * 73984 + kj * 2176 + kl * 64 + ks * 32;  // (ki*34+kj)*34+kl)*64
        const unsigned short* xp = xt + pbase + koff;
        b0[buf] = *(const short8*)xp;
        b1[buf] = *(const short8*)(xp + 1024);
        const unsigned short* wp = wpack + s * 4608 + wbase;    // s*9*512
#pragma unroll
        for (int nf = 0; nf < 9; ++nf)
            a[buf][nf] = *(const short8*)(wp + nf * 512);
    };

    loadstep(0, 0);
    for (int s = 0; s < 54; s += 2) {
        loadstep(s + 1, 1);
#pragma unroll
        for (int nf = 0; nf < 9; ++nf) {
            acc[nf][0] = __builtin_amdgcn_mfma_f32_16x16x32_bf16(a[0][nf], b0[0], acc[nf][0], 0, 0, 0);
            acc[nf][1] = __builtin_amdgcn_mfma_f32_16x16x32_bf16(a[0][nf], b1[0], acc[nf][1], 0, 0, 0);
        }
        if (s + 2 < 54) loadstep(s + 2, 0);
#pragma unroll
        for (int nf = 0; nf < 9; ++nf) {
            acc[nf][0] = __builtin_amdgcn_mfma_f32_16x16x32_bf16(a[1][nf], b0[1], acc[nf][0], 0, 0, 0);
            acc[nf][1] = __builtin_amdgcn_mfma_f32_16x16x32_bf16(a[1][nf], b1[1], acc[nf][1], 0, 0, 0);
        }
    }

#pragma unroll
    for (int f = 0; f < 2; ++f) {
        int w = f * 16 + l16;
        int p = d * 1024 + h * 32 + w;
#pragma unroll
        for (int nf = 0; nf < 9; ++nf) {
#pragma unroll
            for (int r = 0; r < 4; ++r) {
                int o = nf * 16 + quad * 4 + r;
                float v = acc[nf][f][r];
                if (o < 128) {
                    float c = v + bias[o];
                    if (use_cbuf) cbuf[((size_t)(b * 128 + o) << 15) + p] = f2bf(c);
                    else          out[((size_t)(b * 128 + o) << 15) + p] = c;
                } else {
                    low[((size_t)(b * 16 + (o - 128)) << 15) + p] = v;
                }
            }
        }
    }
}

// fl[b][r][p] = 27-neighbor sum of low (bounds-checked, unpadded low)
__global__ __launch_bounds__(256) void foldlow_kernel(const float* __restrict__ low,
                                                      float* __restrict__ fl) {
    int gid = blockIdx.x * 256 + threadIdx.x;   // 4096 blocks
    int p = gid & 32767;
    int r = (gid >> 15) & 15;
    int b = gid >> 19;
    int d = p >> 10, h = (p >> 5) & 31, w = p & 31;
    const float* base = low + ((size_t)(b * 16 + r) << 15);
    float s = 0.f;
    for (int dd = -1; dd <= 1; ++dd) {
        int sd = d + dd;
        if ((unsigned)sd >= 32u) continue;
        for (int dh = -1; dh <= 1; ++dh) {
            int sh = h + dh;
            if ((unsigned)sh >= 32u) continue;
            for (int dw = -1; dw <= 1; ++dw) {
                int sw = w + dw;
                if ((unsigned)sw >= 32u) continue;
                s += base[(sd << 10) + (sh << 5) + sw];
            }
        }
    }
    fl[gid] = s;
}

// out[b][o][p] = conv(b,o,p) + 2 * sum_r lora_B[o][r] * fl[b][r][p]
__global__ __launch_bounds__(256) void mix_kernel(const float* __restrict__ fl,
                                                  const float* __restrict__ loraB,
                                                  const unsigned short* __restrict__ cbuf,
                                                  float* __restrict__ out,
                                                  int use_cbuf) {
    __shared__ float lB[2048];
    int t = threadIdx.x;
    for (int i = t; i < 2048; i += 256) lB[i] = loraB[i];
    __syncthreads();

    int wv = t >> 6;
    int lane = t & 63;
    int P = blockIdx.x * 64 + lane;   // 1024 blocks cover 65536 positions
    int b = P >> 15;
    int p = P & 32767;

    float f[16];
#pragma unroll
    for (int r = 0; r < 16; ++r) f[r] = fl[((size_t)(b * 16 + r) << 15) + p];

    int o0 = wv * 32;
#pragma unroll
    for (int oi = 0; oi < 32; ++oi) {
        int o = o0 + oi;
        float s = 0.f;
#pragma unroll
        for (int r = 0; r < 16; ++r) s += lB[o * 16 + r] * f[r];
        size_t idx = ((size_t)(b * 128 + o) << 15) + p;
        float c = use_cbuf ? __uint_as_float((unsigned)cbuf[idx] << 16) : out[idx];
        out[idx] = c + 2.0f * s;
    }
}

extern "C" void kernel_launch(void* const* d_in, const int* in_sizes, int n_in,
                              void* d_out, int out_size, void* d_ws, size_t ws_size,
                              hipStream_t stream) {
    const float* x      = (const float*)d_in[0];
    const float* weight = (const float*)d_in[1];
    const float* bias   = (const float*)d_in[2];
    const float* loraA  = (const float*)d_in[3];
    const float* loraB  = (const float*)d_in[4];
    float* out = (float*)d_out;

    char* ws = (char*)d_ws;
    unsigned short* xt    = (unsigned short*)ws;                  // 10,061,824 B
    unsigned short* wpack = (unsigned short*)(ws + 10061824);     //    497,664 B
    float* low            = (float*)(ws + 10559488);              //  4,194,304 B
    float* fl             = (float*)(ws + 14753792);              //  4,194,304 B
    unsigned short* cbuf  = (unsigned short*)(ws + 18948096);     // 16,777,216 B
    int use_cbuf = (ws_size >= 35725312u) ? 1 : 0;

    hipLaunchKernelGGL(prep_kernel, dim3(1454), dim3(256), 0, stream, x, weight, loraA, xt, wpack);
    hipLaunchKernelGGL(gemm_kernel, dim3(512), dim3(256), 0, stream, xt, wpack, bias, out, cbuf, low, use_cbuf);
    hipLaunchKernelGGL(foldlow_kernel, dim3(4096), dim3(256), 0, stream, low, fl);
    hipLaunchKernelGGL(mix_kernel, dim3(1024), dim3(256), 0, stream, fl, loraB, cbuf, out, use_cbuf);
}